// Round 3
// baseline (619.859 us; speedup 1.0000x reference)
//
#include <hip/hip_runtime.h>
#include <stdint.h>

#define NTOK 16384
#define DDIM 4096
#define NEXP 128
#define BM 32
#define BK 64

typedef __attribute__((ext_vector_type(8))) short short8;   // 8 bf16 (MFMA A/B frag)
typedef __attribute__((ext_vector_type(4))) float f32x4;    // MFMA C/D frag

union V16 { uint4 u; short8 s; };

__device__ __forceinline__ uint32_t bf16_rne(float f) {
    uint32_t u = __float_as_uint(f);
    return (u + 0x7FFFu + ((u >> 16) & 1u)) >> 16;
}

// fp32 -> (hi, lo) bf16: f ~= hi + lo, residual exact (Sterbenz), |err| <~ 2^-17 |f|
__device__ __forceinline__ void split_bf16(float f, uint32_t& h, uint32_t& l) {
    h = bf16_rne(f);
    float r = f - __uint_as_float(h << 16);
    l = bf16_rne(r);
}

// split 8 consecutive fp32 into packed bf16-hi / bf16-lo fragments
__device__ __forceinline__ void split8(float4 f0, float4 f1, short8& hi, short8& lo) {
    float a[8] = {f0.x, f0.y, f0.z, f0.w, f1.x, f1.y, f1.z, f1.w};
    uint32_t h[8], l[8];
    #pragma unroll
    for (int j = 0; j < 8; ++j) split_bf16(a[j], h[j], l[j]);
    V16 H, L;
    H.u = make_uint4(h[0] | (h[1] << 16), h[2] | (h[3] << 16),
                     h[4] | (h[5] << 16), h[6] | (h[7] << 16));
    L.u = make_uint4(l[0] | (l[1] << 16), l[2] | (l[3] << 16),
                     l[4] | (l[5] << 16), l[6] | (l[7] << 16));
    hi = H.s; lo = L.s;
}

// ---- kernel 1: split wg_weight [128][4096] fp32 -> w_hi, w_lo bf16 in ws ----
__global__ void prep_w(const float* __restrict__ w,
                       uint16_t* __restrict__ whi, uint16_t* __restrict__ wlo) {
    int i = (blockIdx.x * blockDim.x + threadIdx.x) * 4;
    float4 f = *(const float4*)(w + i);
    uint32_t h0, h1, h2, h3, l0, l1, l2, l3;
    split_bf16(f.x, h0, l0);
    split_bf16(f.y, h1, l1);
    split_bf16(f.z, h2, l2);
    split_bf16(f.w, h3, l3);
    *(uint2*)(whi + i) = make_uint2(h0 | (h1 << 16), h2 | (h3 << 16));
    *(uint2*)(wlo + i) = make_uint2(l0 | (l1 << 16), l2 | (l3 << 16));
}

// load one k-step's A (fp32, 2 float4 per frag) and B (pre-split bf16 hi/lo) into regs
__device__ __forceinline__ void load_set(const float* xa0, const float* xa1,
                                         const uint16_t* __restrict__ wh,
                                         const uint16_t* __restrict__ wl,
                                         size_t b0, size_t b1, int k0,
                                         float4* a, uint4* b) {
    #pragma unroll
    for (int mt = 0; mt < 2; ++mt) {
        const float* base = (mt ? xa1 : xa0) + k0;
        #pragma unroll
        for (int ks = 0; ks < 2; ++ks) {
            a[mt * 4 + ks * 2 + 0] = *(const float4*)(base + ks * 32);
            a[mt * 4 + ks * 2 + 1] = *(const float4*)(base + ks * 32 + 4);
        }
    }
    #pragma unroll
    for (int nt = 0; nt < 2; ++nt) {
        const size_t off = (nt ? b1 : b0) + k0;
        #pragma unroll
        for (int ks = 0; ks < 2; ++ks) {
            b[nt * 4 + ks * 2 + 0] = *(const uint4*)(wh + off + ks * 32);
            b[nt * 4 + ks * 2 + 1] = *(const uint4*)(wl + off + ks * 32);
        }
    }
}

// split A in-reg and run the 3-product MFMA block for one 64-wide k-step
__device__ __forceinline__ void compute_set(const float4* a, const uint4* b,
                                            f32x4 acc[2][2]) {
    #pragma unroll
    for (int ks = 0; ks < 2; ++ks) {
        short8 ah[2], al[2];
        #pragma unroll
        for (int mt = 0; mt < 2; ++mt)
            split8(a[mt * 4 + ks * 2], a[mt * 4 + ks * 2 + 1], ah[mt], al[mt]);
        #pragma unroll
        for (int mt = 0; mt < 2; ++mt)
            #pragma unroll
            for (int nt = 0; nt < 2; ++nt) {
                V16 bh, bl;
                bh.u = b[nt * 4 + ks * 2 + 0];
                bl.u = b[nt * 4 + ks * 2 + 1];
                acc[mt][nt] = __builtin_amdgcn_mfma_f32_16x16x32_bf16(al[mt], bh.s, acc[mt][nt], 0, 0, 0);
                acc[mt][nt] = __builtin_amdgcn_mfma_f32_16x16x32_bf16(ah[mt], bl.s, acc[mt][nt], 0, 0, 0);
                acc[mt][nt] = __builtin_amdgcn_mfma_f32_16x16x32_bf16(ah[mt], bh.s, acc[mt][nt], 0, 0, 0);
            }
    }
}

// ---- kernel 2: barrier-free wave-private GEMM + fused softmax/adaptive-top-k ----
// 512 blocks x 256 thr; block: 32 tokens x 128 experts; wave: 32 tok x 32 exp.
// No LDS / no __syncthreads in the k-loop: per-wave vmcnt pipelining only.
__global__ __launch_bounds__(256, 2) void gate_fused(
    const float* __restrict__ x,
    const uint16_t* __restrict__ whi, const uint16_t* __restrict__ wlo,
    const float* __restrict__ mask,
    float* __restrict__ S, float* __restrict__ topk_out)
{
    __shared__ float L[BM][NEXP];   // 16 KB, epilogue-only

    const int tid  = threadIdx.x;
    const int lane = tid & 63;
    const int wave = tid >> 6;
    const int m0   = blockIdx.x * BM;
    const int q    = lane >> 4;     // k-chunk selector within 32-wide step
    const int c    = lane & 15;     // A row / B col within 16

    const float mk0 = mask[lane];
    const float mk1 = mask[lane + 64];

    // A operand addressing (m120 layout: A[m=lane&15][k=quad*8+j])
    const float* xa0 = x + (size_t)(m0 + c) * DDIM + q * 8;
    const float* xa1 = xa0 + (size_t)16 * DDIM;
    // B operand: wave-private 32 experts
    const size_t b0 = (size_t)(wave * 32 + c) * DDIM + q * 8;
    const size_t b1 = b0 + (size_t)16 * DDIM;

    f32x4 acc[2][2];
    #pragma unroll
    for (int mt = 0; mt < 2; ++mt)
        #pragma unroll
        for (int nt = 0; nt < 2; ++nt)
            acc[mt][nt] = (f32x4){0.f, 0.f, 0.f, 0.f};

    float4 aR[8], aN[8];
    uint4  bR[8], bN[8];
    load_set(xa0, xa1, whi, wlo, b0, b1, 0, aR, bR);

    for (int k0 = 0; k0 < DDIM; k0 += 2 * BK) {
        load_set(xa0, xa1, whi, wlo, b0, b1, k0 + BK, aN, bN);
        compute_set(aR, bR, acc);
        const int k2 = (k0 + 2 * BK < DDIM) ? (k0 + 2 * BK) : 0;  // last trip: dead load
        load_set(xa0, xa1, whi, wlo, b0, b1, k2, aR, bR);
        compute_set(aN, bN, acc);
    }

    // ---- epilogue: accs -> LDS logit tile (C/D: col=lane&15, row=(lane>>4)*4+reg) ----
    #pragma unroll
    for (int mt = 0; mt < 2; ++mt)
        #pragma unroll
        for (int nt = 0; nt < 2; ++nt) {
            const int e = wave * 32 + nt * 16 + c;
            #pragma unroll
            for (int r = 0; r < 4; ++r)
                L[mt * 16 + q * 4 + r][e] = acc[mt][nt][r];
        }
    __syncthreads();

    // ---- fused postproc: each wave handles 8 tokens ----
    const bool a0 = (mk0 != 0.f), a1 = (mk1 != 0.f);
    const int active = __popcll(__ballot(a0)) + __popcll(__ballot(a1));

    for (int i = 0; i < 8; ++i) {
        const int lt  = wave * 8 + i;
        const int tok = m0 + lt;
        float s0 = L[lt][lane], s1 = L[lt][lane + 64];

        float mx = fmaxf(a0 ? s0 : -3.0e38f, a1 ? s1 : -3.0e38f);
        #pragma unroll
        for (int off = 32; off; off >>= 1) mx = fmaxf(mx, __shfl_xor(mx, off));

        float p0 = a0 ? __expf(s0 - mx) : 0.f;
        float p1 = a1 ? __expf(s1 - mx) : 0.f;
        float sum = p0 + p1;
        #pragma unroll
        for (int off = 32; off; off >>= 1) sum += __shfl_xor(sum, off);

        const float inv = 1.0f / sum;
        const float sc0 = p0 * inv + 1e-14f;
        const float sc1 = p1 * inv + 1e-14f;
        S[(size_t)tok * NEXP + lane]      = sc0;
        S[(size_t)tok * NEXP + lane + 64] = sc1;

        // adaptive top-k: extract maxima until cum >= 0.5 (matches sorted-cumsum order)
        float v0 = sc0, v1 = sc1;
        float cum = 0.f;
        int k = 0;
        while (cum < 0.5f && k < NEXP) {
            float mv = fmaxf(v0, v1);
            #pragma unroll
            for (int off = 32; off; off >>= 1) mv = fmaxf(mv, __shfl_xor(mv, off));
            cum += mv;
            ++k;
            unsigned long long bt = __ballot(v0 == mv || v1 == mv);
            int first = __ffsll(bt) - 1;
            if (lane == first) {
                if (v0 == mv) v0 = -1.f; else v1 = -1.f;
            }
        }
        int topk = k < active ? k : active;
        if (lane == 0) topk_out[tok] = (float)topk;
    }
}

extern "C" void kernel_launch(void* const* d_in, const int* in_sizes, int n_in,
                              void* d_out, int out_size, void* d_ws, size_t ws_size,
                              hipStream_t stream) {
    (void)in_sizes; (void)n_in; (void)out_size; (void)ws_size;
    const float* x    = (const float*)d_in[0];
    const float* w    = (const float*)d_in[1];
    const float* mask = (const float*)d_in[2];

    float* S    = (float*)d_out;                  // [16384,128] scores
    float* topk = S + (size_t)NTOK * NEXP;        // [16384] top_k as float

    uint16_t* whi = (uint16_t*)d_ws;              // [128,4096] bf16 hi
    uint16_t* wlo = whi + (size_t)NEXP * DDIM;    // [128,4096] bf16 lo

    hipLaunchKernelGGL(prep_w, dim3((NEXP * DDIM) / (256 * 4)), dim3(256), 0, stream,
                       w, whi, wlo);
    hipLaunchKernelGGL(gate_fused, dim3(NTOK / BM), dim3(256), 0, stream,
                       x, whi, wlo, mask, S, topk);
}

// Round 4
// 456.217 us; speedup vs baseline: 1.3587x; 1.3587x over previous
//
#include <hip/hip_runtime.h>
#include <stdint.h>

#define NTOK 16384
#define DDIM 4096
#define NEXP 128
#define BM 16
#define BK 64
#define BKP 72  // padded A row stride (144 B = 9*16B): 16B-aligned reads, 2-way banks only

typedef __attribute__((ext_vector_type(8))) short short8;   // 8 bf16 (MFMA A/B frag)
typedef __attribute__((ext_vector_type(4))) float f32x4;    // MFMA C/D frag

__device__ __forceinline__ uint32_t bf16_rne(float f) {
    uint32_t u = __float_as_uint(f);
    return (u + 0x7FFFu + ((u >> 16) & 1u)) >> 16;
}

// fp32 -> (hi, lo) bf16: f ~= hi + lo, residual exact (Sterbenz), |err| <~ 2^-17 |f|
__device__ __forceinline__ void split_bf16(float f, uint32_t& h, uint32_t& l) {
    h = bf16_rne(f);
    float r = f - __uint_as_float(h << 16);
    l = bf16_rne(r);
}

// async global->LDS, 16 B/lane; LDS dest = wave-uniform base + lane*16
__device__ __forceinline__ void gld_lds16(const void* g, void* l) {
    __builtin_amdgcn_global_load_lds(
        (const __attribute__((address_space(1))) void*)g,
        (__attribute__((address_space(3))) void*)l, 16, 0, 0);
}

// ---- kernel 1: split wg_weight [128][4096] fp32 -> w_hi, w_lo bf16 in ws ----
__global__ void prep_w(const float* __restrict__ w,
                       uint16_t* __restrict__ whi, uint16_t* __restrict__ wlo) {
    int i = (blockIdx.x * blockDim.x + threadIdx.x) * 4;
    float4 f = *(const float4*)(w + i);
    uint32_t h0, h1, h2, h3, l0, l1, l2, l3;
    split_bf16(f.x, h0, l0);
    split_bf16(f.y, h1, l1);
    split_bf16(f.z, h2, l2);
    split_bf16(f.w, h3, l3);
    *(uint2*)(whi + i) = make_uint2(h0 | (h1 << 16), h2 | (h3 << 16));
    *(uint2*)(wlo + i) = make_uint2(l0 | (l1 << 16), l2 | (l3 << 16));
}

// ---- kernel 2: logits GEMM, BM=16 x 128 experts per block, 1024 blocks (4/CU) ----
// 4 waves, each owns 16 tokens x 32 experts (1x2 tiles of 16x16x32, 3-product split-bf16)
__global__ __launch_bounds__(256, 4) void gate_gemm(
    const float* __restrict__ x,
    const uint16_t* __restrict__ whi, const uint16_t* __restrict__ wlo,
    float* __restrict__ S)
{
    __shared__ uint16_t sAh[BM * BKP], sAl[BM * BKP];   // 2.3 KB each, padded
    __shared__ uint16_t sBh[NEXP * BK], sBl[NEXP * BK]; // 16 KB each, linear+swizzled
    // total 36.6 KB -> 4 blocks/CU

    const int tid  = threadIdx.x;
    const int lane = tid & 63;
    const int wave = tid >> 6;
    const int m0   = blockIdx.x * BM;
    const int q    = lane >> 4;     // quad id (k-group selector)
    const int c    = lane & 15;     // A row / B col within 16

    // A staging: thread t -> row am = t>>4 (16 rows), 4-elem chunk akc = t&15
    const int am  = tid >> 4;
    const int akc = tid & 15;
    const float* xp = x + (size_t)(m0 + am) * DDIM + akc * 4;

    // preload first A chunk
    float4 fa = *(const float4*)(xp);

    f32x4 acc[2];
    acc[0] = (f32x4){0.f, 0.f, 0.f, 0.f};
    acc[1] = (f32x4){0.f, 0.f, 0.f, 0.f};

    // B async-copy ids: 1024 chunks of 8 bf16 per buffer; 4 instrs/lane/buffer
    int bn[4], bkc[4];
    #pragma unroll
    for (int j = 0; j < 4; ++j) {
        const int p = (wave * 4 + j) * 64 + lane;   // LDS chunk this lane fills
        bn[j]  = p >> 3;                            // expert row 0..127
        bkc[j] = (p & 7) ^ (bn[j] & 7);             // swizzled k-chunk
    }

    for (int k0 = 0; k0 < DDIM; k0 += BK) {
        // ---- stage A: split fp32 -> bf16 hi/lo -> padded LDS (4 elems/thread) ----
        uint32_t h0, h1, h2, h3, l0, l1, l2, l3;
        split_bf16(fa.x, h0, l0);
        split_bf16(fa.y, h1, l1);
        split_bf16(fa.z, h2, l2);
        split_bf16(fa.w, h3, l3);
        *(uint2*)&sAh[am * BKP + akc * 4] = make_uint2(h0 | (h1 << 16), h2 | (h3 << 16));
        *(uint2*)&sAl[am * BKP + akc * 4] = make_uint2(l0 | (l1 << 16), l2 | (l3 << 16));

        // ---- stage B: async global->LDS, source-address swizzled ----
        #pragma unroll
        for (int j = 0; j < 4; ++j) {
            const size_t go = (size_t)bn[j] * DDIM + k0 + bkc[j] * 8;
            const int lb = (wave * 4 + j) * 512;    // uniform LDS elem base (1 KB/instr)
            gld_lds16(whi + go, sBh + lb);
            gld_lds16(wlo + go, sBl + lb);
        }
        __syncthreads();

        // ---- prefetch next A chunk (lands during MFMA block) ----
        {
            const int kn = (k0 + BK < DDIM) ? (k0 + BK) : 0;  // last trip: dead reload
            fa = *(const float4*)(xp + kn);
        }

        // ---- compute: 2 k-steps of 32, 1x2 tiles, 3 MFMAs each ----
        #pragma unroll
        for (int ks = 0; ks < 2; ++ks) {
            const int kb  = ks * 32 + q * 8;  // A elem offset in row
            const int kb8 = ks * 4 + q;       // B k-chunk index
            short8 ah, al, bh[2], bl[2];
            {
                const int ro = c * BKP + kb;
                ah = *(const short8*)&sAh[ro];
                al = *(const short8*)&sAl[ro];
            }
            #pragma unroll
            for (int nt = 0; nt < 2; ++nt) {
                const int ne = wave * 32 + nt * 16 + c;          // expert row
                const int ch = ne * 8 + (kb8 ^ (ne & 7));        // swizzled chunk
                bh[nt] = *(const short8*)&sBh[ch * 8];
                bl[nt] = *(const short8*)&sBl[ch * 8];
            }
            #pragma unroll
            for (int nt = 0; nt < 2; ++nt) {
                acc[nt] = __builtin_amdgcn_mfma_f32_16x16x32_bf16(al, bh[nt], acc[nt], 0, 0, 0);
                acc[nt] = __builtin_amdgcn_mfma_f32_16x16x32_bf16(ah, bl[nt], acc[nt], 0, 0, 0);
                acc[nt] = __builtin_amdgcn_mfma_f32_16x16x32_bf16(ah, bh[nt], acc[nt], 0, 0, 0);
            }
        }
        __syncthreads();
    }

    // ---- epilogue: C/D layout col=lane&15 (expert), row=(lane>>4)*4+reg (token) ----
    #pragma unroll
    for (int nt = 0; nt < 2; ++nt) {
        const int e = wave * 32 + nt * 16 + c;
        #pragma unroll
        for (int r = 0; r < 4; ++r) {
            const int tok = m0 + q * 4 + r;
            S[(size_t)tok * NEXP + e] = acc[nt][r];
        }
    }
}

// ---- kernel 3: masked softmax + adaptive top-k, one wave per token ----
__global__ __launch_bounds__(256) void postproc(
    float* __restrict__ S, const float* __restrict__ mask,
    float* __restrict__ topk_out)
{
    const int lane = threadIdx.x & 63;
    const int wave = threadIdx.x >> 6;
    const int t = blockIdx.x * 4 + wave;
    float* row = S + (size_t)t * NEXP;

    float s0 = row[lane], s1 = row[lane + 64];
    float mk0 = mask[lane], mk1 = mask[lane + 64];
    const bool a0 = (mk0 != 0.f), a1 = (mk1 != 0.f);

    float mx = fmaxf(a0 ? s0 : -3.0e38f, a1 ? s1 : -3.0e38f);
    #pragma unroll
    for (int off = 32; off; off >>= 1) mx = fmaxf(mx, __shfl_xor(mx, off));

    float p0 = a0 ? __expf(s0 - mx) : 0.f;
    float p1 = a1 ? __expf(s1 - mx) : 0.f;
    float sum = p0 + p1;
    #pragma unroll
    for (int off = 32; off; off >>= 1) sum += __shfl_xor(sum, off);

    const float inv = 1.0f / sum;
    const float sc0 = p0 * inv + 1e-14f;
    const float sc1 = p1 * inv + 1e-14f;
    row[lane]      = sc0;
    row[lane + 64] = sc1;

    const int active = __popcll(__ballot(a0)) + __popcll(__ballot(a1));

    // adaptive top-k: extract maxima until cum >= 0.5 (matches sorted-cumsum order)
    float v0 = sc0, v1 = sc1;
    float cum = 0.f;
    int k = 0;
    while (cum < 0.5f && k < NEXP) {
        float mv = fmaxf(v0, v1);
        #pragma unroll
        for (int off = 32; off; off >>= 1) mv = fmaxf(mv, __shfl_xor(mv, off));
        cum += mv;
        ++k;
        unsigned long long b = __ballot(v0 == mv || v1 == mv);
        int first = __ffsll(b) - 1;
        if (lane == first) {
            if (v0 == mv) v0 = -1.f; else v1 = -1.f;
        }
    }
    int topk = k < active ? k : active;
    if (lane == 0) topk_out[t] = (float)topk;
}

extern "C" void kernel_launch(void* const* d_in, const int* in_sizes, int n_in,
                              void* d_out, int out_size, void* d_ws, size_t ws_size,
                              hipStream_t stream) {
    (void)in_sizes; (void)n_in; (void)out_size; (void)ws_size;
    const float* x    = (const float*)d_in[0];
    const float* w    = (const float*)d_in[1];
    const float* mask = (const float*)d_in[2];

    float* S    = (float*)d_out;                  // [16384,128] scores (logits first)
    float* topk = S + (size_t)NTOK * NEXP;        // [16384] top_k as float

    uint16_t* whi = (uint16_t*)d_ws;              // [128,4096] bf16 hi
    uint16_t* wlo = whi + (size_t)NEXP * DDIM;    // [128,4096] bf16 lo

    hipLaunchKernelGGL(prep_w, dim3((NEXP * DDIM) / (256 * 4)), dim3(256), 0, stream,
                       w, whi, wlo);
    hipLaunchKernelGGL(gate_gemm, dim3(NTOK / BM), dim3(256), 0, stream,
                       x, whi, wlo, S);
    hipLaunchKernelGGL(postproc, dim3(NTOK / 4), dim3(256), 0, stream,
                       S, mask, topk);
}

// Round 5
// 418.778 us; speedup vs baseline: 1.4802x; 1.0894x over previous
//
#include <hip/hip_runtime.h>
#include <stdint.h>

#define NTOK 16384
#define DDIM 4096
#define NEXP 128
#define BM 128          // tokens per block
#define BK 64           // k per staged tile
#define KSPLIT 4
#define KSLICE (DDIM / KSPLIT)   // 1024
#define ITERS (KSLICE / BK)      // 16
#define BKP 72          // padded A row stride (144 B = 9*16B)

typedef __attribute__((ext_vector_type(8))) short short8;   // 8 bf16 (MFMA A/B frag)
typedef __attribute__((ext_vector_type(4))) float f32x4;    // MFMA C/D frag

union V16 { uint4 u; short8 s; };

__device__ __forceinline__ uint32_t bf16_rne(float f) {
    uint32_t u = __float_as_uint(f);
    return (u + 0x7FFFu + ((u >> 16) & 1u)) >> 16;
}

// fp32 -> (hi, lo) bf16: f ~= hi + lo, residual exact (Sterbenz), |err| <~ 2^-17 |f|
__device__ __forceinline__ void split_bf16(float f, uint32_t& h, uint32_t& l) {
    h = bf16_rne(f);
    float r = f - __uint_as_float(h << 16);
    l = bf16_rne(r);
}

// split 8 consecutive fp32 into packed bf16 hi / lo 16-byte groups
__device__ __forceinline__ void split8(float4 f0, float4 f1, uint4& hi, uint4& lo) {
    float a[8] = {f0.x, f0.y, f0.z, f0.w, f1.x, f1.y, f1.z, f1.w};
    uint32_t h[8], l[8];
    #pragma unroll
    for (int j = 0; j < 8; ++j) split_bf16(a[j], h[j], l[j]);
    hi = make_uint4(h[0] | (h[1] << 16), h[2] | (h[3] << 16),
                    h[4] | (h[5] << 16), h[6] | (h[7] << 16));
    lo = make_uint4(l[0] | (l[1] << 16), l[2] | (l[3] << 16),
                    l[4] | (l[5] << 16), l[6] | (l[7] << 16));
}

// async global->LDS, 16 B/lane; LDS dest = wave-uniform base + lane*16
__device__ __forceinline__ void gld_lds16(const void* g, void* l) {
    __builtin_amdgcn_global_load_lds(
        (const __attribute__((address_space(1))) void*)g,
        (__attribute__((address_space(3))) void*)l, 16, 0, 0);
}

// ---- kernel 1: split wg_weight [128][4096] fp32 -> w_hi, w_lo bf16 in ws ----
__global__ void prep_w(const float* __restrict__ w,
                       uint16_t* __restrict__ whi, uint16_t* __restrict__ wlo) {
    int i = (blockIdx.x * blockDim.x + threadIdx.x) * 4;
    float4 f = *(const float4*)(w + i);
    uint32_t h0, h1, h2, h3, l0, l1, l2, l3;
    split_bf16(f.x, h0, l0);
    split_bf16(f.y, h1, l1);
    split_bf16(f.z, h2, l2);
    split_bf16(f.w, h3, l3);
    *(uint2*)(whi + i) = make_uint2(h0 | (h1 << 16), h2 | (h3 << 16));
    *(uint2*)(wlo + i) = make_uint2(l0 | (l1 << 16), l2 | (l3 << 16));
}

// ---- kernel 2: partial-logits GEMM. Block = 128 tok x 128 exp x 1024 k-slice ----
// Grid 512 (2/CU). 4 waves in 2x2: wave owns 64 tok x 64 exp (4x4 16x16 tiles).
// Per iter: stage A 32 KB (HBM, reg-prefetched) + B 32 KB (L2, async gld_lds).
__global__ __launch_bounds__(256, 2) void gate_gemm(
    const float* __restrict__ x,
    const uint16_t* __restrict__ whi, const uint16_t* __restrict__ wlo,
    float* __restrict__ P)
{
    __shared__ uint16_t sAh[BM * BKP], sAl[BM * BKP];   // 18.4 KB each (padded)
    __shared__ uint16_t sBh[NEXP * BK], sBl[NEXP * BK]; // 16 KB each (linear+swizzled)
    // total 69.6 KB -> 2 blocks/CU

    const int tid  = threadIdx.x;
    const int lane = tid & 63;
    const int wave = tid >> 6;
    const int mg   = blockIdx.x >> 2;       // token group
    const int ksl  = blockIdx.x & 3;        // k slice
    const int m0   = mg * BM;
    const int kbase = ksl * KSLICE;
    const int q = lane >> 4;                // quad (k-group / token-subrow selector)
    const int c = lane & 15;                // A row / B col within 16
    const int mw = wave >> 1;               // wave tile: 64 tok
    const int nw = wave & 1;                //            64 exp

    // A staging: thread t -> row t>>1 (128 rows), k-half (t&1)*32
    const int arow  = tid >> 1;
    const int ahalf = (tid & 1) * 32;
    const float* xp = x + (size_t)(m0 + arow) * DDIM + kbase + ahalf;

    // prefetch iter 0's A chunk (32 fp32 = 8 float4)
    float4 aP[8];
    #pragma unroll
    for (int j = 0; j < 8; ++j) aP[j] = *(const float4*)(xp + j * 4);

    // B async-copy ids: 1024 chunks of 8 bf16 per buffer; 4 instrs/lane/buffer
    int bn[4], bkc[4];
    #pragma unroll
    for (int j = 0; j < 4; ++j) {
        const int p = (wave * 4 + j) * 64 + lane;
        bn[j]  = p >> 3;                    // expert row 0..127
        bkc[j] = (p & 7) ^ (bn[j] & 7);     // swizzled k-chunk
    }

    f32x4 acc[4][4];
    #pragma unroll
    for (int mt = 0; mt < 4; ++mt)
        #pragma unroll
        for (int nt = 0; nt < 4; ++nt)
            acc[mt][nt] = (f32x4){0.f, 0.f, 0.f, 0.f};

    for (int it = 0; it < ITERS; ++it) {
        const int k0 = it * BK;

        // ---- stage A: split prefetched fp32 -> bf16 hi/lo -> padded LDS ----
        #pragma unroll
        for (int j = 0; j < 4; ++j) {
            uint4 hi, lo;
            split8(aP[2 * j], aP[2 * j + 1], hi, lo);
            *(uint4*)&sAh[arow * BKP + ahalf + j * 8] = hi;
            *(uint4*)&sAl[arow * BKP + ahalf + j * 8] = lo;
        }

        // ---- stage B: async global->LDS, source-address swizzled ----
        #pragma unroll
        for (int j = 0; j < 4; ++j) {
            const size_t go = (size_t)bn[j] * DDIM + kbase + k0 + bkc[j] * 8;
            const int lb = (wave * 4 + j) * 512;    // uniform LDS elem base (1 KB/instr)
            gld_lds16(whi + go, sBh + lb);
            gld_lds16(wlo + go, sBl + lb);
        }
        __syncthreads();

        // ---- prefetch next iter's A (lands during MFMA block) ----
        {
            const int kn = (it + 1 < ITERS) ? (k0 + BK) : 0;  // last trip: dead reload
            #pragma unroll
            for (int j = 0; j < 8; ++j) aP[j] = *(const float4*)(xp + kn + j * 4);
        }

        // ---- compute: 2 k-steps of 32; 4x4 tiles; 3 MFMAs each ----
        #pragma unroll
        for (int ks = 0; ks < 2; ++ks) {
            const int kb  = ks * 32 + q * 8;   // A elem offset in row
            const int kb8 = ks * 4 + q;        // B k-chunk index
            short8 ah[4], al[4];
            #pragma unroll
            for (int mt = 0; mt < 4; ++mt) {
                const int ro = (mw * 64 + mt * 16 + c) * BKP + kb;
                ah[mt] = *(const short8*)&sAh[ro];
                al[mt] = *(const short8*)&sAl[ro];
            }
            #pragma unroll
            for (int nt = 0; nt < 4; ++nt) {
                const int ne = nw * 64 + nt * 16 + c;          // expert row
                const int ch = ne * 8 + (kb8 ^ (ne & 7));      // swizzled chunk
                short8 bh = *(const short8*)&sBh[ch * 8];
                short8 bl = *(const short8*)&sBl[ch * 8];
                #pragma unroll
                for (int mt = 0; mt < 4; ++mt) {
                    acc[mt][nt] = __builtin_amdgcn_mfma_f32_16x16x32_bf16(al[mt], bh, acc[mt][nt], 0, 0, 0);
                    acc[mt][nt] = __builtin_amdgcn_mfma_f32_16x16x32_bf16(ah[mt], bl, acc[mt][nt], 0, 0, 0);
                    acc[mt][nt] = __builtin_amdgcn_mfma_f32_16x16x32_bf16(ah[mt], bh, acc[mt][nt], 0, 0, 0);
                }
            }
        }
        __syncthreads();
    }

    // ---- epilogue: partials. C/D layout col=lane&15 (expert), row=q*4+reg (token) ----
    float* Pp = P + (size_t)ksl * NTOK * NEXP;
    #pragma unroll
    for (int mt = 0; mt < 4; ++mt)
        #pragma unroll
        for (int nt = 0; nt < 4; ++nt) {
            const int e = nw * 64 + nt * 16 + c;
            #pragma unroll
            for (int r = 0; r < 4; ++r) {
                const int tok = m0 + mw * 64 + mt * 16 + q * 4 + r;
                Pp[(size_t)tok * NEXP + e] = acc[mt][nt][r];
            }
        }
}

// ---- kernel 3: sum k-slice partials + masked softmax + adaptive top-k ----
__global__ __launch_bounds__(256) void postproc(
    const float* __restrict__ P, const float* __restrict__ mask,
    float* __restrict__ S, float* __restrict__ topk_out)
{
    const int lane = threadIdx.x & 63;
    const int wave = threadIdx.x >> 6;
    const int t = blockIdx.x * 4 + wave;

    float s0 = 0.f, s1 = 0.f;
    #pragma unroll
    for (int ks = 0; ks < KSPLIT; ++ks) {
        const float* row = P + ((size_t)ks * NTOK + t) * NEXP;
        s0 += row[lane];
        s1 += row[lane + 64];
    }

    float mk0 = mask[lane], mk1 = mask[lane + 64];
    const bool a0 = (mk0 != 0.f), a1 = (mk1 != 0.f);

    float mx = fmaxf(a0 ? s0 : -3.0e38f, a1 ? s1 : -3.0e38f);
    #pragma unroll
    for (int off = 32; off; off >>= 1) mx = fmaxf(mx, __shfl_xor(mx, off));

    float p0 = a0 ? __expf(s0 - mx) : 0.f;
    float p1 = a1 ? __expf(s1 - mx) : 0.f;
    float sum = p0 + p1;
    #pragma unroll
    for (int off = 32; off; off >>= 1) sum += __shfl_xor(sum, off);

    const float inv = 1.0f / sum;
    const float sc0 = p0 * inv + 1e-14f;
    const float sc1 = p1 * inv + 1e-14f;
    float* out = S + (size_t)t * NEXP;
    out[lane]      = sc0;
    out[lane + 64] = sc1;

    const int active = __popcll(__ballot(a0)) + __popcll(__ballot(a1));

    // adaptive top-k: extract maxima until cum >= 0.5 (matches sorted-cumsum order)
    float v0 = sc0, v1 = sc1;
    float cum = 0.f;
    int k = 0;
    while (cum < 0.5f && k < NEXP) {
        float mv = fmaxf(v0, v1);
        #pragma unroll
        for (int off = 32; off; off >>= 1) mv = fmaxf(mv, __shfl_xor(mv, off));
        cum += mv;
        ++k;
        unsigned long long b = __ballot(v0 == mv || v1 == mv);
        int first = __ffsll(b) - 1;
        if (lane == first) {
            if (v0 == mv) v0 = -1.f; else v1 = -1.f;
        }
    }
    int topk = k < active ? k : active;
    if (lane == 0) topk_out[t] = (float)topk;
}

extern "C" void kernel_launch(void* const* d_in, const int* in_sizes, int n_in,
                              void* d_out, int out_size, void* d_ws, size_t ws_size,
                              hipStream_t stream) {
    (void)in_sizes; (void)n_in; (void)out_size; (void)ws_size;
    const float* x    = (const float*)d_in[0];
    const float* w    = (const float*)d_in[1];
    const float* mask = (const float*)d_in[2];

    float* S    = (float*)d_out;                  // [16384,128] scores
    float* topk = S + (size_t)NTOK * NEXP;        // [16384] top_k as float

    uint16_t* whi = (uint16_t*)d_ws;              // [128,4096] bf16 hi
    uint16_t* wlo = whi + (size_t)NEXP * DDIM;    // [128,4096] bf16 lo
    float* P = (float*)(wlo + (size_t)NEXP * DDIM);  // [4][16384][128] fp32 partials (32 MB)

    hipLaunchKernelGGL(prep_w, dim3((NEXP * DDIM) / (256 * 4)), dim3(256), 0, stream,
                       w, whi, wlo);
    hipLaunchKernelGGL(gate_gemm, dim3((NTOK / BM) * KSPLIT), dim3(256), 0, stream,
                       x, whi, wlo, P);
    hipLaunchKernelGGL(postproc, dim3(NTOK / 4), dim3(256), 0, stream,
                       P, mask, S, topk);
}